// Round 5
// baseline (504.173 us; speedup 1.0000x reference)
//
#include <hip/hip_runtime.h>

#define DIM 256
#define DOUT 64
#define PSPLITS 16

typedef short bf16x8 __attribute__((ext_vector_type(8)));
typedef float f32x4 __attribute__((ext_vector_type(4)));
typedef unsigned short u16x8 __attribute__((ext_vector_type(8)));

// ---- bf16 helpers (bit-level, RNE) ----
static __device__ __forceinline__ float b2f(unsigned short u) {
    return __uint_as_float(((unsigned)u) << 16);
}
static __device__ __forceinline__ unsigned short f2bf(float f) {
    unsigned u = __float_as_uint(f);
    unsigned r = (u + 0x7fffu + ((u >> 16) & 1u)) >> 16;
    return (unsigned short)r;
}

// ---------------- convert x (f32) -> h (bf16) ----------------
__global__ void cvt_f32_bf16(const float4* __restrict__ src, ushort4* __restrict__ dst, int n4) {
    int i = blockIdx.x * blockDim.x + threadIdx.x;
    int stride = gridDim.x * blockDim.x;
    for (; i < n4; i += stride) {
        float4 v = src[i];
        ushort4 o;
        o.x = f2bf(v.x); o.y = f2bf(v.y); o.z = f2bf(v.z); o.w = f2bf(v.w);
        dst[i] = o;
    }
}

__global__ void copy_i32(const int* __restrict__ src, int* __restrict__ dst, int n) {
    int i = blockIdx.x * blockDim.x + threadIdx.x;
    if (i < n) dst[i] = src[i];
}

// ---------------- CSR build ----------------
__global__ void hist_kernel(const int* __restrict__ dst, int* __restrict__ deg, int E) {
    int i = blockIdx.x * blockDim.x + threadIdx.x;
    if (i < E) atomicAdd(&deg[dst[i]], 1);
}

__global__ void scan_kernel(const int* __restrict__ deg, int* __restrict__ row_ptr, int n) {
    __shared__ int sums[256];
    int t = threadIdx.x;
    int chunk = (n + 255) / 256;
    int lo = t * chunk;
    int hi = min(lo + chunk, n);
    int s = 0;
    for (int i = lo; i < hi; ++i) s += deg[i];
    sums[t] = s;
    __syncthreads();
    for (int off = 1; off < 256; off <<= 1) {
        int v = (t >= off) ? sums[t - off] : 0;
        __syncthreads();
        sums[t] += v;
        __syncthreads();
    }
    int excl = (t == 0) ? 0 : sums[t - 1];
    int run = excl;
    for (int i = lo; i < hi; ++i) { row_ptr[i] = run; run += deg[i]; }
    if (t == 255) row_ptr[n] = run;
}

__global__ void scatter_kernel(const int* __restrict__ src, const int* __restrict__ dst,
                               int* __restrict__ cursor, int* __restrict__ perm, int E) {
    int i = blockIdx.x * blockDim.x + threadIdx.x;
    if (i < E) {
        int d = dst[i];
        int p = atomicAdd(&cursor[d], 1);
        perm[p] = src[i];
    }
}

// ---------------- transpose + convert W [K][N] f32 -> Wt [N][K] bf16 ----------------
__global__ void transpose_w(const float* __restrict__ W, unsigned short* __restrict__ Wt) {
    __shared__ float tile[32][33];
    int l = blockIdx.z;
    int k0 = blockIdx.x * 32, n0 = blockIdx.y * 32;
    const float* Wl = W + (size_t)l * DIM * DIM;
    unsigned short* Wtl = Wt + (size_t)l * DIM * DIM;
    int tx = threadIdx.x, ty = threadIdx.y;
    for (int i = ty; i < 32; i += 8)
        tile[i][tx] = Wl[(size_t)(k0 + i) * DIM + n0 + tx];
    __syncthreads();
    for (int i = ty; i < 32; i += 8)
        Wtl[(size_t)(n0 + i) * DIM + k0 + tx] = f2bf(tile[tx][i]);
}

// ---------------- aggregation (bf16): z = h + sum_{e: dst=n} h[src[e]] ----------------
__global__ void agg_kernel(const ushort4* __restrict__ h4, const int* __restrict__ row_ptr,
                           const int* __restrict__ perm, ushort4* __restrict__ z4, int n) {
    int wave = threadIdx.x >> 6;
    int lane = threadIdx.x & 63;
    int node = blockIdx.x * 4 + wave;
    if (node >= n) return;
    size_t base = (size_t)node * 64 + lane;
    ushort4 hv = h4[base];
    float ax = b2f(hv.x), ay = b2f(hv.y), az = b2f(hv.z), aw = b2f(hv.w);
    int lo = row_ptr[node], hi = row_ptr[node + 1];
    int e = lo;
    for (; e + 8 <= hi; e += 8) {
        ushort4 v[8];
#pragma unroll
        for (int j = 0; j < 8; ++j) {
            int s = perm[e + j];
            v[j] = h4[(size_t)s * 64 + lane];
        }
#pragma unroll
        for (int j = 0; j < 8; ++j) {
            ax += b2f(v[j].x); ay += b2f(v[j].y);
            az += b2f(v[j].z); aw += b2f(v[j].w);
        }
    }
    for (; e < hi; ++e) {
        int s0 = perm[e];
        ushort4 v0 = h4[(size_t)s0 * 64 + lane];
        ax += b2f(v0.x); ay += b2f(v0.y); az += b2f(v0.z); aw += b2f(v0.w);
    }
    ushort4 o;
    o.x = f2bf(ax); o.y = f2bf(ay); o.z = f2bf(az); o.w = f2bf(aw);
    z4[base] = o;
}

// ---------------- fused per-layer MLP: H = act(relu(Z@W1+b1)@W2+b2) ----------------
template <bool RELU>
__global__ __launch_bounds__(256) void fused_mlp(const unsigned short* __restrict__ Z,
                                                 const unsigned short* __restrict__ Wt1,
                                                 const float* __restrict__ b1,
                                                 const unsigned short* __restrict__ Wt2,
                                                 const float* __restrict__ b2,
                                                 unsigned short* __restrict__ H, int M) {
    __shared__ unsigned char lds[49152];
    char* Tl = (char*)lds;               // [64 rows][512 B] swizzled: byte ^= (row&7)<<4
    char* Bs = (char*)lds + 32768;       // [4 kseg][256 col][16 B]

    const int tid = threadIdx.x;
    const int wave = tid >> 6;
    const int lane = tid & 63;
    const int l15 = lane & 15;
    const int g4 = lane >> 4;            // 0..3
    const int lk8 = g4 * 8;
    const int m0 = blockIdx.x * 64;
    const int scol = tid;                // staging column

    // hoist all 8 z A-frags (row = m0 + wave*16 + l15)
    const int rowA = min(m0 + wave * 16 + l15, M - 1);
    bf16x8 a[8];
#pragma unroll
    for (int kb8 = 0; kb8 < 8; ++kb8)
        a[kb8] = *reinterpret_cast<const bf16x8*>(&Z[(size_t)rowA * 256 + kb8 * 32 + lk8]);

    u16x8 st[4];
#define LDREG(WT, KB8)                                                            \
    {                                                                             \
        _Pragma("unroll") for (int j = 0; j < 4; ++j)                             \
            st[j] = *reinterpret_cast<const u16x8*>(                              \
                &(WT)[(size_t)scol * 256 + (KB8) * 32 + j * 8]);                  \
    }
#define WLDS()                                                                    \
    {                                                                             \
        _Pragma("unroll") for (int j = 0; j < 4; ++j)                             \
            *reinterpret_cast<u16x8*>(Bs + j * 4096 + scol * 16) = st[j];         \
    }

    f32x4 acc[16];
#pragma unroll
    for (int i = 0; i < 16; ++i) acc[i] = (f32x4){0.f, 0.f, 0.f, 0.f};

    LDREG(Wt1, 0);
    // ---- phase 1: t = relu(z@W1 + b1) ----
    for (int kb8 = 0; kb8 < 8; ++kb8) {
        __syncthreads();                 // previous step's Bs readers done
        WLDS();
        if (kb8 < 7) { LDREG(Wt1, kb8 + 1); } else { LDREG(Wt2, 0); }
        __syncthreads();                 // Bs ready
#pragma unroll
        for (int nt = 0; nt < 16; ++nt) {
            bf16x8 b = *reinterpret_cast<const bf16x8*>(Bs + g4 * 4096 + (nt * 16 + l15) * 16);
            acc[nt] = __builtin_amdgcn_mfma_f32_16x16x32_bf16(a[kb8], b, acc[nt], 0, 0, 0);
        }
    }

    // write t to swizzled LDS (wave-local rows), reset acc
    {
        const int rb = wave * 16 + g4 * 4;
#pragma unroll
        for (int nt = 0; nt < 16; ++nt) {
            int col = nt * 16 + l15;
            float bv = b1[col];
#pragma unroll
            for (int r = 0; r < 4; ++r) {
                int row = rb + r;
                float v = fmaxf(acc[nt][r] + bv, 0.f);
                *(unsigned short*)(Tl + row * 512 + ((col * 2) ^ ((row & 7) << 4))) = f2bf(v);
            }
            acc[nt] = (f32x4){0.f, 0.f, 0.f, 0.f};
        }
    }

    const int rowT = wave * 16 + l15;    // local t row for phase-2 A-frags
    // ---- phase 2: h = act(t@W2 + b2) ----
    for (int kb8 = 0; kb8 < 8; ++kb8) {
        __syncthreads();
        WLDS();
        if (kb8 < 7) LDREG(Wt2, kb8 + 1);
        __syncthreads();
        bf16x8 a2 = *reinterpret_cast<const bf16x8*>(
            Tl + rowT * 512 + (((kb8 * 32 + lk8) * 2) ^ ((rowT & 7) << 4)));
#pragma unroll
        for (int nt = 0; nt < 16; ++nt) {
            bf16x8 b = *reinterpret_cast<const bf16x8*>(Bs + g4 * 4096 + (nt * 16 + l15) * 16);
            acc[nt] = __builtin_amdgcn_mfma_f32_16x16x32_bf16(a2, b, acc[nt], 0, 0, 0);
        }
    }

    // epilogue: h -> global
    {
        const int rb = m0 + wave * 16 + g4 * 4;
#pragma unroll
        for (int nt = 0; nt < 16; ++nt) {
            int col = nt * 16 + l15;
            float bv = b2[col];
#pragma unroll
            for (int r = 0; r < 4; ++r) {
                int row = rb + r;
                if (row < M) {
                    float v = acc[nt][r] + bv;
                    if (RELU) v = fmaxf(v, 0.f);
                    H[(size_t)row * 256 + col] = f2bf(v);
                }
            }
        }
    }
#undef LDREG
#undef WLDS
}

// ---------------- pooling ----------------
__global__ void gstart_kernel(const int* __restrict__ bids, int* __restrict__ gstart,
                              int n, int G) {
    int g = blockIdx.x * blockDim.x + threadIdx.x;
    if (g > G) return;
    if (g == G) { gstart[G] = n; return; }
    int lo = 0, hi = n;
    while (lo < hi) {
        int mid = (lo + hi) >> 1;
        if (bids[mid] < g) lo = mid + 1; else hi = mid;
    }
    gstart[g] = lo;
}

__global__ void pool_kernel(const ushort4* __restrict__ h4, const int* __restrict__ gstart,
                            float* __restrict__ pooled) {
    int g = blockIdx.x;
    int split = blockIdx.y;
    int lane = threadIdx.x;   // 0..63
    int lo = gstart[g], hi = gstart[g + 1];
    int cnt = hi - lo;
    int chunk = (cnt + PSPLITS - 1) / PSPLITS;
    int s0 = lo + split * chunk;
    int s1 = min(s0 + chunk, hi);
    if (s0 >= s1) return;
    float ax = 0.f, ay = 0.f, az = 0.f, aw = 0.f;
    for (int nd = s0; nd < s1; ++nd) {
        ushort4 v = h4[(size_t)nd * 64 + lane];
        ax += b2f(v.x); ay += b2f(v.y); az += b2f(v.z); aw += b2f(v.w);
    }
    float* p = &pooled[(size_t)g * DIM + lane * 4];
    atomicAdd(p + 0, ax);
    atomicAdd(p + 1, ay);
    atomicAdd(p + 2, az);
    atomicAdd(p + 3, aw);
}

__global__ void out_kernel(const float* __restrict__ pooled, const float* __restrict__ Wout,
                           const float* __restrict__ bout, float* __restrict__ out) {
    __shared__ float p[DIM];
    int g = blockIdx.x;
    for (int d = threadIdx.x; d < DIM; d += blockDim.x) p[d] = pooled[(size_t)g * DIM + d];
    __syncthreads();
    int o = threadIdx.x;
    if (o < DOUT) {
        float acc = bout[o];
        for (int d = 0; d < DIM; ++d) acc += p[d] * Wout[(size_t)d * DOUT + o];
        out[(size_t)g * DOUT + o] = acc;
    }
}

// ---------------- launch ----------------
extern "C" void kernel_launch(void* const* d_in, const int* in_sizes, int n_in,
                              void* d_out, int out_size, void* d_ws, size_t ws_size,
                              hipStream_t stream) {
    const float* x    = (const float*)d_in[0];
    const int*   esrc = (const int*)d_in[1];
    const int*   edst = (const int*)d_in[2];
    const int*   bids = (const int*)d_in[3];
    const float* W1   = (const float*)d_in[4];
    const float* b1   = (const float*)d_in[5];
    const float* W2   = (const float*)d_in[6];
    const float* b2   = (const float*)d_in[7];
    const float* Wout = (const float*)d_in[8];
    const float* bout = (const float*)d_in[9];

    const int N = in_sizes[3];             // 20000
    const int E = in_sizes[1];             // 320000
    const int L = in_sizes[5] / DIM;       // 4
    const int G = out_size / (DOUT + DIM); // 128

    char* ws = (char*)d_ws;
    size_t off = 0;
    auto carve = [&](size_t bytes) -> char* {
        char* p = ws + off;
        off = (off + bytes + 255) & ~(size_t)255;
        return p;
    };
    int* row_ptr = (int*)carve((size_t)(N + 1) * sizeof(int));
    int* cursor  = (int*)carve((size_t)N * sizeof(int));
    int* perm    = (int*)carve((size_t)E * sizeof(int));
    int* gstart  = (int*)carve((size_t)(G + 1) * sizeof(int));
    unsigned short* h   = (unsigned short*)carve((size_t)N * DIM * 2);
    unsigned short* z   = (unsigned short*)carve((size_t)N * DIM * 2);
    unsigned short* wt1 = (unsigned short*)carve((size_t)L * DIM * DIM * 2);
    unsigned short* wt2 = (unsigned short*)carve((size_t)L * DIM * DIM * 2);
    (void)ws_size;

    // h = bf16(x)
    cvt_f32_bf16<<<2048, 256, 0, stream>>>((const float4*)x, (ushort4*)h, N * (DIM / 4));

    // CSR build (cursor doubles as degree scratch)
    hipMemsetAsync(cursor, 0, (size_t)N * sizeof(int), stream);
    hist_kernel<<<(E + 255) / 256, 256, 0, stream>>>(edst, cursor, E);
    scan_kernel<<<1, 256, 0, stream>>>(cursor, row_ptr, N);
    copy_i32<<<(N + 255) / 256, 256, 0, stream>>>(row_ptr, cursor, N);
    scatter_kernel<<<(E + 255) / 256, 256, 0, stream>>>(esrc, edst, cursor, perm, E);

    // Wt = bf16(W^T) for both MLP weight sets
    {
        dim3 tgrid(DIM / 32, DIM / 32, L);
        dim3 tblk(32, 8);
        transpose_w<<<tgrid, tblk, 0, stream>>>(W1, wt1);
        transpose_w<<<tgrid, tblk, 0, stream>>>(W2, wt2);
    }

    const int mlp_grid = (N + 63) / 64;
    for (int l = 0; l < L; ++l) {
        agg_kernel<<<(N + 3) / 4, 256, 0, stream>>>((const ushort4*)h, row_ptr, perm,
                                                    (ushort4*)z, N);
        if (l < L - 1)
            fused_mlp<true><<<mlp_grid, 256, 0, stream>>>(
                z, wt1 + (size_t)l * DIM * DIM, b1 + (size_t)l * DIM,
                wt2 + (size_t)l * DIM * DIM, b2 + (size_t)l * DIM, h, N);
        else
            fused_mlp<false><<<mlp_grid, 256, 0, stream>>>(
                z, wt1 + (size_t)l * DIM * DIM, b1 + (size_t)l * DIM,
                wt2 + (size_t)l * DIM * DIM, b2 + (size_t)l * DIM, h, N);
    }

    float* outp   = (float*)d_out;
    float* pooled = outp + (size_t)G * DOUT;
    hipMemsetAsync(pooled, 0, (size_t)G * DIM * sizeof(float), stream);
    gstart_kernel<<<1, 256, 0, stream>>>(bids, gstart, N, G);
    {
        dim3 pgrid(G, PSPLITS);
        pool_kernel<<<pgrid, 64, 0, stream>>>((const ushort4*)h, gstart, pooled);
    }
    out_kernel<<<G, 64, 0, stream>>>(pooled, Wout, bout, outp);
}

// Round 6
// 337.740 us; speedup vs baseline: 1.4928x; 1.4928x over previous
//
#include <hip/hip_runtime.h>

#define DIM 256
#define DOUT 64
#define PSPLITS 16

typedef short bf16x8 __attribute__((ext_vector_type(8)));
typedef float f32x4 __attribute__((ext_vector_type(4)));
typedef unsigned short u16x8 __attribute__((ext_vector_type(8)));

// ---- bf16 helpers (bit-level, RNE) ----
static __device__ __forceinline__ float b2f(unsigned short u) {
    return __uint_as_float(((unsigned)u) << 16);
}
static __device__ __forceinline__ unsigned short f2bf(float f) {
    unsigned u = __float_as_uint(f);
    unsigned r = (u + 0x7fffu + ((u >> 16) & 1u)) >> 16;
    return (unsigned short)r;
}

// ---------------- convert x (f32) -> h (bf16) ----------------
__global__ void cvt_f32_bf16(const float4* __restrict__ src, ushort4* __restrict__ dst, int n4) {
    int i = blockIdx.x * blockDim.x + threadIdx.x;
    int stride = gridDim.x * blockDim.x;
    for (; i < n4; i += stride) {
        float4 v = src[i];
        ushort4 o;
        o.x = f2bf(v.x); o.y = f2bf(v.y); o.z = f2bf(v.z); o.w = f2bf(v.w);
        dst[i] = o;
    }
}

__global__ void copy_i32(const int* __restrict__ src, int* __restrict__ dst, int n) {
    int i = blockIdx.x * blockDim.x + threadIdx.x;
    if (i < n) dst[i] = src[i];
}

// ---------------- CSR build ----------------
__global__ void hist_kernel(const int* __restrict__ dst, int* __restrict__ deg, int E) {
    int i = blockIdx.x * blockDim.x + threadIdx.x;
    if (i < E) atomicAdd(&deg[dst[i]], 1);
}

__global__ void scan_kernel(const int* __restrict__ deg, int* __restrict__ row_ptr, int n) {
    __shared__ int sums[256];
    int t = threadIdx.x;
    int chunk = (n + 255) / 256;
    int lo = t * chunk;
    int hi = min(lo + chunk, n);
    int s = 0;
    for (int i = lo; i < hi; ++i) s += deg[i];
    sums[t] = s;
    __syncthreads();
    for (int off = 1; off < 256; off <<= 1) {
        int v = (t >= off) ? sums[t - off] : 0;
        __syncthreads();
        sums[t] += v;
        __syncthreads();
    }
    int excl = (t == 0) ? 0 : sums[t - 1];
    int run = excl;
    for (int i = lo; i < hi; ++i) { row_ptr[i] = run; run += deg[i]; }
    if (t == 255) row_ptr[n] = run;
}

__global__ void scatter_kernel(const int* __restrict__ src, const int* __restrict__ dst,
                               int* __restrict__ cursor, int* __restrict__ perm, int E) {
    int i = blockIdx.x * blockDim.x + threadIdx.x;
    if (i < E) {
        int d = dst[i];
        int p = atomicAdd(&cursor[d], 1);
        perm[p] = src[i];
    }
}

// ---------------- transpose + convert W [K][N] f32 -> Wt [N][K] bf16 ----------------
__global__ void transpose_w(const float* __restrict__ W, unsigned short* __restrict__ Wt) {
    __shared__ float tile[32][33];
    int l = blockIdx.z;
    int k0 = blockIdx.x * 32, n0 = blockIdx.y * 32;
    const float* Wl = W + (size_t)l * DIM * DIM;
    unsigned short* Wtl = Wt + (size_t)l * DIM * DIM;
    int tx = threadIdx.x, ty = threadIdx.y;
    for (int i = ty; i < 32; i += 8)
        tile[i][tx] = Wl[(size_t)(k0 + i) * DIM + n0 + tx];
    __syncthreads();
    for (int i = ty; i < 32; i += 8)
        Wtl[(size_t)(n0 + i) * DIM + k0 + tx] = f2bf(tile[tx][i]);
}

// ---------------- aggregation (bf16): z = h + sum_{e: dst=n} h[src[e]] ----------------
__global__ void agg_kernel(const ushort4* __restrict__ h4, const int* __restrict__ row_ptr,
                           const int* __restrict__ perm, ushort4* __restrict__ z4, int n) {
    int wave = threadIdx.x >> 6;
    int lane = threadIdx.x & 63;
    int node = blockIdx.x * 4 + wave;
    if (node >= n) return;
    size_t base = (size_t)node * 64 + lane;
    ushort4 hv = h4[base];
    float ax = b2f(hv.x), ay = b2f(hv.y), az = b2f(hv.z), aw = b2f(hv.w);
    int lo = row_ptr[node], hi = row_ptr[node + 1];
    int e = lo;
    for (; e + 8 <= hi; e += 8) {
        ushort4 v[8];
#pragma unroll
        for (int j = 0; j < 8; ++j) {
            int s = perm[e + j];
            v[j] = h4[(size_t)s * 64 + lane];
        }
#pragma unroll
        for (int j = 0; j < 8; ++j) {
            ax += b2f(v[j].x); ay += b2f(v[j].y);
            az += b2f(v[j].z); aw += b2f(v[j].w);
        }
    }
    for (; e < hi; ++e) {
        int s0 = perm[e];
        ushort4 v0 = h4[(size_t)s0 * 64 + lane];
        ax += b2f(v0.x); ay += b2f(v0.y); az += b2f(v0.z); aw += b2f(v0.w);
    }
    ushort4 o;
    o.x = f2bf(ax); o.y = f2bf(ay); o.z = f2bf(az); o.w = f2bf(aw);
    z4[base] = o;
}

// ---------------- bf16 MFMA GEMM with LDS-staged B-tile + hoisted A ----------------
// Block: BM=128 rows x BN=64 cols, 4 waves; wave w = rows [w*32, w*32+32), all 64 cols.
// All 16 A-frags (2 m-tiles x 8 k-steps) loaded from global BEFORE the K-loop;
// K-loop is pure {4 ds_read_b128 + 8 MFMA}. B-tile (64x256 bf16 = 32 KB) in LDS,
// XOR swizzle byte ^= (col&7)<<4 -> conflict-free frag reads.
template <bool RELU>
__global__ __launch_bounds__(256) void mfma_gemm(const unsigned short* __restrict__ A,
                                                 const unsigned short* __restrict__ Bt,
                                                 const float* __restrict__ bias,
                                                 unsigned short* __restrict__ C, int M) {
    __shared__ unsigned short Bs[64 * 256];   // [col][k] swizzled, 32 KB
    const int tid = threadIdx.x;
    const int wave = tid >> 6;
    const int lane = tid & 63;
    const int l15 = lane & 15;
    const int lk8 = (lane >> 4) * 8;          // 0,8,16,24 (k elems)
    const int m_base = blockIdx.x * 128 + wave * 32;
    const int n_blk = blockIdx.y * 64;

    // ---- stage B-tile: thread t loads col=t>>2, 128B segment seg=t&3 ----
    {
        const int col = tid >> 2;
        const int seg = tid & 3;
        const unsigned short* gsrc = &Bt[(size_t)(n_blk + col) * 256 + seg * 64];
        char* lbase = (char*)Bs + col * 512;
        const int sw = (col & 7) << 4;
#pragma unroll
        for (int j = 0; j < 8; ++j) {
            int kbyte = seg * 128 + j * 16;
            *reinterpret_cast<u16x8*>(lbase + (kbyte ^ sw)) =
                *reinterpret_cast<const u16x8*>((const char*)gsrc + j * 16);
        }
    }

    // ---- hoist all A-frags (overlaps with B staging; no barrier yet) ----
    bf16x8 a[2][8];
#pragma unroll
    for (int m = 0; m < 2; ++m) {
        int r = min(m_base + m * 16 + l15, M - 1);
        const unsigned short* arow = &A[(size_t)r * 256];
#pragma unroll
        for (int kb8 = 0; kb8 < 8; ++kb8)
            a[m][kb8] = *reinterpret_cast<const bf16x8*>(arow + kb8 * 32 + lk8);
    }

    __syncthreads();

    f32x4 acc[2][4] = {};

#pragma unroll
    for (int kb8 = 0; kb8 < 8; ++kb8) {
        bf16x8 b[4];
#pragma unroll
        for (int n = 0; n < 4; ++n) {
            int col = n * 16 + l15;
            int kbyte = (kb8 * 32 + lk8) * 2;
            b[n] = *reinterpret_cast<const bf16x8*>(
                (const char*)Bs + col * 512 + (kbyte ^ ((col & 7) << 4)));
        }
#pragma unroll
        for (int m = 0; m < 2; ++m)
#pragma unroll
            for (int n = 0; n < 4; ++n)
                acc[m][n] = __builtin_amdgcn_mfma_f32_16x16x32_bf16(a[m][kb8], b[n],
                                                                    acc[m][n], 0, 0, 0);
    }

    // C/D layout: col = lane&15, row = (lane>>4)*4 + reg
#pragma unroll
    for (int n = 0; n < 4; ++n) {
        int col = n_blk + n * 16 + l15;
        float bv = bias[col];
#pragma unroll
        for (int m = 0; m < 2; ++m) {
#pragma unroll
            for (int r = 0; r < 4; ++r) {
                int row = m_base + m * 16 + (lane >> 4) * 4 + r;
                if (row < M) {
                    float v = acc[m][n][r] + bv;
                    if (RELU) v = fmaxf(v, 0.f);
                    C[(size_t)row * 256 + col] = f2bf(v);
                }
            }
        }
    }
}

// ---------------- pooling ----------------
__global__ void gstart_kernel(const int* __restrict__ bids, int* __restrict__ gstart,
                              int n, int G) {
    int g = blockIdx.x * blockDim.x + threadIdx.x;
    if (g > G) return;
    if (g == G) { gstart[G] = n; return; }
    int lo = 0, hi = n;
    while (lo < hi) {
        int mid = (lo + hi) >> 1;
        if (bids[mid] < g) lo = mid + 1; else hi = mid;
    }
    gstart[g] = lo;
}

__global__ void pool_kernel(const ushort4* __restrict__ h4, const int* __restrict__ gstart,
                            float* __restrict__ pooled) {
    int g = blockIdx.x;
    int split = blockIdx.y;
    int lane = threadIdx.x;   // 0..63
    int lo = gstart[g], hi = gstart[g + 1];
    int cnt = hi - lo;
    int chunk = (cnt + PSPLITS - 1) / PSPLITS;
    int s0 = lo + split * chunk;
    int s1 = min(s0 + chunk, hi);
    if (s0 >= s1) return;
    float ax = 0.f, ay = 0.f, az = 0.f, aw = 0.f;
    for (int nd = s0; nd < s1; ++nd) {
        ushort4 v = h4[(size_t)nd * 64 + lane];
        ax += b2f(v.x); ay += b2f(v.y); az += b2f(v.z); aw += b2f(v.w);
    }
    float* p = &pooled[(size_t)g * DIM + lane * 4];
    atomicAdd(p + 0, ax);
    atomicAdd(p + 1, ay);
    atomicAdd(p + 2, az);
    atomicAdd(p + 3, aw);
}

__global__ void out_kernel(const float* __restrict__ pooled, const float* __restrict__ Wout,
                           const float* __restrict__ bout, float* __restrict__ out) {
    __shared__ float p[DIM];
    int g = blockIdx.x;
    for (int d = threadIdx.x; d < DIM; d += blockDim.x) p[d] = pooled[(size_t)g * DIM + d];
    __syncthreads();
    int o = threadIdx.x;
    if (o < DOUT) {
        float acc = bout[o];
        for (int d = 0; d < DIM; ++d) acc += p[d] * Wout[(size_t)d * DOUT + o];
        out[(size_t)g * DOUT + o] = acc;
    }
}

// ---------------- launch ----------------
extern "C" void kernel_launch(void* const* d_in, const int* in_sizes, int n_in,
                              void* d_out, int out_size, void* d_ws, size_t ws_size,
                              hipStream_t stream) {
    const float* x    = (const float*)d_in[0];
    const int*   esrc = (const int*)d_in[1];
    const int*   edst = (const int*)d_in[2];
    const int*   bids = (const int*)d_in[3];
    const float* W1   = (const float*)d_in[4];
    const float* b1   = (const float*)d_in[5];
    const float* W2   = (const float*)d_in[6];
    const float* b2   = (const float*)d_in[7];
    const float* Wout = (const float*)d_in[8];
    const float* bout = (const float*)d_in[9];

    const int N = in_sizes[3];             // 20000
    const int E = in_sizes[1];             // 320000
    const int L = in_sizes[5] / DIM;       // 4
    const int G = out_size / (DOUT + DIM); // 128

    char* ws = (char*)d_ws;
    size_t off = 0;
    auto carve = [&](size_t bytes) -> char* {
        char* p = ws + off;
        off = (off + bytes + 255) & ~(size_t)255;
        return p;
    };
    int* row_ptr = (int*)carve((size_t)(N + 1) * sizeof(int));
    int* cursor  = (int*)carve((size_t)N * sizeof(int));
    int* perm    = (int*)carve((size_t)E * sizeof(int));
    int* gstart  = (int*)carve((size_t)(G + 1) * sizeof(int));
    unsigned short* h   = (unsigned short*)carve((size_t)N * DIM * 2);
    unsigned short* z   = (unsigned short*)carve((size_t)N * DIM * 2);
    unsigned short* t   = (unsigned short*)carve((size_t)N * DIM * 2);
    unsigned short* wt1 = (unsigned short*)carve((size_t)L * DIM * DIM * 2);
    unsigned short* wt2 = (unsigned short*)carve((size_t)L * DIM * DIM * 2);
    (void)ws_size;

    // h = bf16(x)
    cvt_f32_bf16<<<2048, 256, 0, stream>>>((const float4*)x, (ushort4*)h, N * (DIM / 4));

    // CSR build (cursor doubles as degree scratch)
    hipMemsetAsync(cursor, 0, (size_t)N * sizeof(int), stream);
    hist_kernel<<<(E + 255) / 256, 256, 0, stream>>>(edst, cursor, E);
    scan_kernel<<<1, 256, 0, stream>>>(cursor, row_ptr, N);
    copy_i32<<<(N + 255) / 256, 256, 0, stream>>>(row_ptr, cursor, N);
    scatter_kernel<<<(E + 255) / 256, 256, 0, stream>>>(esrc, edst, cursor, perm, E);

    // Wt = bf16(W^T) for both MLP weight sets
    {
        dim3 tgrid(DIM / 32, DIM / 32, L);
        dim3 tblk(32, 8);
        transpose_w<<<tgrid, tblk, 0, stream>>>(W1, wt1);
        transpose_w<<<tgrid, tblk, 0, stream>>>(W2, wt2);
    }

    dim3 ggrid((N + 127) / 128, 4);
    for (int l = 0; l < L; ++l) {
        agg_kernel<<<(N + 3) / 4, 256, 0, stream>>>((const ushort4*)h, row_ptr, perm,
                                                    (ushort4*)z, N);
        mfma_gemm<true><<<ggrid, 256, 0, stream>>>(
            z, wt1 + (size_t)l * DIM * DIM, b1 + (size_t)l * DIM, t, N);
        if (l < L - 1)
            mfma_gemm<true><<<ggrid, 256, 0, stream>>>(
                t, wt2 + (size_t)l * DIM * DIM, b2 + (size_t)l * DIM, h, N);
        else
            mfma_gemm<false><<<ggrid, 256, 0, stream>>>(
                t, wt2 + (size_t)l * DIM * DIM, b2 + (size_t)l * DIM, h, N);
    }

    float* outp   = (float*)d_out;
    float* pooled = outp + (size_t)G * DOUT;
    hipMemsetAsync(pooled, 0, (size_t)G * DIM * sizeof(float), stream);
    gstart_kernel<<<1, 256, 0, stream>>>(bids, gstart, N, G);
    {
        dim3 pgrid(G, PSPLITS);
        pool_kernel<<<pgrid, 64, 0, stream>>>((const ushort4*)h, gstart, pooled);
    }
    out_kernel<<<G, 64, 0, stream>>>(pooled, Wout, bout, outp);
}

// Round 7
// 287.187 us; speedup vs baseline: 1.7556x; 1.1760x over previous
//
#include <hip/hip_runtime.h>

#define DIM 256
#define DOUT 64
#define PSPLITS 16

typedef short bf16x8 __attribute__((ext_vector_type(8)));
typedef float f32x4 __attribute__((ext_vector_type(4)));
typedef unsigned short u16x8 __attribute__((ext_vector_type(8)));

// ---- bf16 helpers (bit-level, RNE) ----
static __device__ __forceinline__ float b2f(unsigned short u) {
    return __uint_as_float(((unsigned)u) << 16);
}
static __device__ __forceinline__ unsigned short f2bf(float f) {
    unsigned u = __float_as_uint(f);
    unsigned r = (u + 0x7fffu + ((u >> 16) & 1u)) >> 16;
    return (unsigned short)r;
}

// ---------------- convert x (f32) -> h (bf16) ----------------
__global__ void cvt_f32_bf16(const float4* __restrict__ src, ushort4* __restrict__ dst, int n4) {
    int i = blockIdx.x * blockDim.x + threadIdx.x;
    int stride = gridDim.x * blockDim.x;
    for (; i < n4; i += stride) {
        float4 v = src[i];
        ushort4 o;
        o.x = f2bf(v.x); o.y = f2bf(v.y); o.z = f2bf(v.z); o.w = f2bf(v.w);
        dst[i] = o;
    }
}

__global__ void copy_i32(const int* __restrict__ src, int* __restrict__ dst, int n) {
    int i = blockIdx.x * blockDim.x + threadIdx.x;
    if (i < n) dst[i] = src[i];
}

// ---------------- CSR build ----------------
__global__ void hist_kernel(const int* __restrict__ dst, int* __restrict__ deg, int E) {
    int i = blockIdx.x * blockDim.x + threadIdx.x;
    if (i < E) atomicAdd(&deg[dst[i]], 1);
}

__global__ void scan_kernel(const int* __restrict__ deg, int* __restrict__ row_ptr, int n) {
    __shared__ int sums[256];
    int t = threadIdx.x;
    int chunk = (n + 255) / 256;
    int lo = t * chunk;
    int hi = min(lo + chunk, n);
    int s = 0;
    for (int i = lo; i < hi; ++i) s += deg[i];
    sums[t] = s;
    __syncthreads();
    for (int off = 1; off < 256; off <<= 1) {
        int v = (t >= off) ? sums[t - off] : 0;
        __syncthreads();
        sums[t] += v;
        __syncthreads();
    }
    int excl = (t == 0) ? 0 : sums[t - 1];
    int run = excl;
    for (int i = lo; i < hi; ++i) { row_ptr[i] = run; run += deg[i]; }
    if (t == 255) row_ptr[n] = run;
}

__global__ void scatter_kernel(const int* __restrict__ src, const int* __restrict__ dst,
                               int* __restrict__ cursor, int* __restrict__ perm, int E) {
    int i = blockIdx.x * blockDim.x + threadIdx.x;
    if (i < E) {
        int d = dst[i];
        int p = atomicAdd(&cursor[d], 1);
        perm[p] = src[i];
    }
}

// ---------------- transpose + convert W [K][N] f32 -> Wt [N][K] bf16 ----------------
__global__ void transpose_w(const float* __restrict__ W, unsigned short* __restrict__ Wt) {
    __shared__ float tile[32][33];
    int l = blockIdx.z;
    int k0 = blockIdx.x * 32, n0 = blockIdx.y * 32;
    const float* Wl = W + (size_t)l * DIM * DIM;
    unsigned short* Wtl = Wt + (size_t)l * DIM * DIM;
    int tx = threadIdx.x, ty = threadIdx.y;
    for (int i = ty; i < 32; i += 8)
        tile[i][tx] = Wl[(size_t)(k0 + i) * DIM + n0 + tx];
    __syncthreads();
    for (int i = ty; i < 32; i += 8)
        Wtl[(size_t)(n0 + i) * DIM + k0 + tx] = f2bf(tile[tx][i]);
}

// ---------------- aggregation (bf16): z = h + sum_{e: dst=n} h[src[e]] ----------------
__global__ void agg_kernel(const ushort4* __restrict__ h4, const int* __restrict__ row_ptr,
                           const int* __restrict__ perm, ushort4* __restrict__ z4, int n) {
    int wave = threadIdx.x >> 6;
    int lane = threadIdx.x & 63;
    int node = blockIdx.x * 4 + wave;
    if (node >= n) return;
    size_t base = (size_t)node * 64 + lane;
    ushort4 hv = h4[base];
    float ax = b2f(hv.x), ay = b2f(hv.y), az = b2f(hv.z), aw = b2f(hv.w);
    int lo = row_ptr[node], hi = row_ptr[node + 1];
    int e = lo;
    for (; e + 8 <= hi; e += 8) {
        ushort4 v[8];
#pragma unroll
        for (int j = 0; j < 8; ++j) {
            int s = perm[e + j];
            v[j] = h4[(size_t)s * 64 + lane];
        }
#pragma unroll
        for (int j = 0; j < 8; ++j) {
            ax += b2f(v[j].x); ay += b2f(v[j].y);
            az += b2f(v[j].z); aw += b2f(v[j].w);
        }
    }
    for (; e < hi; ++e) {
        int s0 = perm[e];
        ushort4 v0 = h4[(size_t)s0 * 64 + lane];
        ax += b2f(v0.x); ay += b2f(v0.y); az += b2f(v0.z); aw += b2f(v0.w);
    }
    ushort4 o;
    o.x = f2bf(ax); o.y = f2bf(ay); o.z = f2bf(az); o.w = f2bf(aw);
    z4[base] = o;
}

// ---------------- persistent reg-B bf16 MFMA GEMM ----------------
// Grid = 256 blocks x 4 waves. Block b: W-half = b&1 (cols half*128..+128, 64 KB LDS),
// m-slice = b>>1. Wave w: n-panel = half*128 + (w&1)*64; m-tiles t = (mslice*2+(w>>1)) + 256*i.
// Wave reg-caches its 64x256 B-panel (32 bf16x8 = 128 VGPR); main loop has NO LDS/barrier:
// {prefetch next A-frags from global, 32 MFMA, store 16x64 C tile}.
template <bool RELU>
__global__ __launch_bounds__(256, 2) void mfma_gemm(const unsigned short* __restrict__ A,
                                                    const unsigned short* __restrict__ Bt,
                                                    const float* __restrict__ bias,
                                                    unsigned short* __restrict__ C, int M) {
    __shared__ unsigned short Bs[128 * 256];   // [col][k] swizzled, 64 KB
    const int tid = threadIdx.x;
    const int wave = tid >> 6;
    const int lane = tid & 63;
    const int l15 = lane & 15;
    const int g4 = lane >> 4;                  // 0..3
    const int half = blockIdx.x & 1;
    const int mslice = blockIdx.x >> 1;
    const int NT = (M + 15) / 16;              // m-tiles (1250)

    // ---- stage W half-panel (128 cols x 256 k) into swizzled LDS ----
    {
        const char* gsrc = (const char*)&Bt[(size_t)half * 128 * 256];
#pragma unroll
        for (int jj = 0; jj < 16; ++jj) {
            int chunk = tid + jj * 256;        // 16B chunks, 4096 total
            int col = chunk >> 5;              // 32 chunks per 512B col
            int kbyte = (chunk & 31) * 16;
            *reinterpret_cast<u16x8*>((char*)Bs + col * 512 + (kbyte ^ ((col & 7) << 4))) =
                *reinterpret_cast<const u16x8*>(gsrc + col * 512 + kbyte);
        }
    }
    __syncthreads();

    // ---- reg-cache this wave's 64-col B panel: b[n][k8] ----
    bf16x8 b[4][8];
#pragma unroll
    for (int n = 0; n < 4; ++n) {
        const int col = (wave & 1) * 64 + n * 16 + l15;  // local col in 128-panel
        const char* cbase = (const char*)Bs + col * 512;
        const int sw = (col & 7) << 4;
#pragma unroll
        for (int k8 = 0; k8 < 8; ++k8) {
            int kbyte = (k8 * 32 + g4 * 8) * 2;
            b[n][k8] = *reinterpret_cast<const bf16x8*>(cbase + (kbyte ^ sw));
        }
    }

    // bias preload
    const int ncol0 = half * 128 + (wave & 1) * 64;
    float bv[4];
#pragma unroll
    for (int n = 0; n < 4; ++n) bv[n] = bias[ncol0 + n * 16 + l15];

    const int base = mslice * 2 + (wave >> 1);  // 0..255

    auto loadA = [&](bf16x8 (&a)[8], int t) {
        int r = t * 16 + l15;
        if (r >= M) r = M - 1;
        const unsigned short* arow = &A[(size_t)r * 256];
#pragma unroll
        for (int k8 = 0; k8 < 8; ++k8)
            a[k8] = *reinterpret_cast<const bf16x8*>(arow + k8 * 32 + g4 * 8);
    };

    auto computeStore = [&](bf16x8 (&a)[8], int t) {
        f32x4 acc[4] = {};
#pragma unroll
        for (int k8 = 0; k8 < 8; ++k8)
#pragma unroll
            for (int n = 0; n < 4; ++n)
                acc[n] = __builtin_amdgcn_mfma_f32_16x16x32_bf16(a[k8], b[n][k8], acc[n], 0, 0, 0);
        int r0 = t * 16 + g4 * 4;
#pragma unroll
        for (int n = 0; n < 4; ++n) {
            int col = ncol0 + n * 16 + l15;
#pragma unroll
            for (int r = 0; r < 4; ++r) {
                int row = r0 + r;
                if (row < M) {
                    float v = acc[n][r] + bv[n];
                    if (RELU) v = fmaxf(v, 0.f);
                    C[(size_t)row * 256 + col] = f2bf(v);
                }
            }
        }
    };

    bf16x8 a0[8], a1[8];
    int t = base;
    if (t >= NT) return;
    loadA(a0, t);
#pragma unroll 1
    for (int rep = 0; rep < 3; ++rep) {
        if (t >= NT) break;
        if (t + 256 < NT) loadA(a1, t + 256);
        computeStore(a0, t);
        t += 256;
        if (t >= NT) break;
        if (t + 256 < NT) loadA(a0, t + 256);
        computeStore(a1, t);
        t += 256;
    }
}

// ---------------- pooling ----------------
__global__ void gstart_kernel(const int* __restrict__ bids, int* __restrict__ gstart,
                              int n, int G) {
    int g = blockIdx.x * blockDim.x + threadIdx.x;
    if (g > G) return;
    if (g == G) { gstart[G] = n; return; }
    int lo = 0, hi = n;
    while (lo < hi) {
        int mid = (lo + hi) >> 1;
        if (bids[mid] < g) lo = mid + 1; else hi = mid;
    }
    gstart[g] = lo;
}

__global__ void pool_kernel(const ushort4* __restrict__ h4, const int* __restrict__ gstart,
                            float* __restrict__ pooled) {
    int g = blockIdx.x;
    int split = blockIdx.y;
    int lane = threadIdx.x;   // 0..63
    int lo = gstart[g], hi = gstart[g + 1];
    int cnt = hi - lo;
    int chunk = (cnt + PSPLITS - 1) / PSPLITS;
    int s0 = lo + split * chunk;
    int s1 = min(s0 + chunk, hi);
    if (s0 >= s1) return;
    float ax = 0.f, ay = 0.f, az = 0.f, aw = 0.f;
    for (int nd = s0; nd < s1; ++nd) {
        ushort4 v = h4[(size_t)nd * 64 + lane];
        ax += b2f(v.x); ay += b2f(v.y); az += b2f(v.z); aw += b2f(v.w);
    }
    float* p = &pooled[(size_t)g * DIM + lane * 4];
    atomicAdd(p + 0, ax);
    atomicAdd(p + 1, ay);
    atomicAdd(p + 2, az);
    atomicAdd(p + 3, aw);
}

__global__ void out_kernel(const float* __restrict__ pooled, const float* __restrict__ Wout,
                           const float* __restrict__ bout, float* __restrict__ out) {
    __shared__ float p[DIM];
    int g = blockIdx.x;
    for (int d = threadIdx.x; d < DIM; d += blockDim.x) p[d] = pooled[(size_t)g * DIM + d];
    __syncthreads();
    int o = threadIdx.x;
    if (o < DOUT) {
        float acc = bout[o];
        for (int d = 0; d < DIM; ++d) acc += p[d] * Wout[(size_t)d * DOUT + o];
        out[(size_t)g * DOUT + o] = acc;
    }
}

// ---------------- launch ----------------
extern "C" void kernel_launch(void* const* d_in, const int* in_sizes, int n_in,
                              void* d_out, int out_size, void* d_ws, size_t ws_size,
                              hipStream_t stream) {
    const float* x    = (const float*)d_in[0];
    const int*   esrc = (const int*)d_in[1];
    const int*   edst = (const int*)d_in[2];
    const int*   bids = (const int*)d_in[3];
    const float* W1   = (const float*)d_in[4];
    const float* b1   = (const float*)d_in[5];
    const float* W2   = (const float*)d_in[6];
    const float* b2   = (const float*)d_in[7];
    const float* Wout = (const float*)d_in[8];
    const float* bout = (const float*)d_in[9];

    const int N = in_sizes[3];             // 20000
    const int E = in_sizes[1];             // 320000
    const int L = in_sizes[5] / DIM;       // 4
    const int G = out_size / (DOUT + DIM); // 128

    char* ws = (char*)d_ws;
    size_t off = 0;
    auto carve = [&](size_t bytes) -> char* {
        char* p = ws + off;
        off = (off + bytes + 255) & ~(size_t)255;
        return p;
    };
    int* row_ptr = (int*)carve((size_t)(N + 1) * sizeof(int));
    int* cursor  = (int*)carve((size_t)N * sizeof(int));
    int* perm    = (int*)carve((size_t)E * sizeof(int));
    int* gstart  = (int*)carve((size_t)(G + 1) * sizeof(int));
    unsigned short* h   = (unsigned short*)carve((size_t)N * DIM * 2);
    unsigned short* z   = (unsigned short*)carve((size_t)N * DIM * 2);
    unsigned short* t   = (unsigned short*)carve((size_t)N * DIM * 2);
    unsigned short* wt1 = (unsigned short*)carve((size_t)L * DIM * DIM * 2);
    unsigned short* wt2 = (unsigned short*)carve((size_t)L * DIM * DIM * 2);
    (void)ws_size;

    // h = bf16(x)
    cvt_f32_bf16<<<2048, 256, 0, stream>>>((const float4*)x, (ushort4*)h, N * (DIM / 4));

    // CSR build (cursor doubles as degree scratch)
    hipMemsetAsync(cursor, 0, (size_t)N * sizeof(int), stream);
    hist_kernel<<<(E + 255) / 256, 256, 0, stream>>>(edst, cursor, E);
    scan_kernel<<<1, 256, 0, stream>>>(cursor, row_ptr, N);
    copy_i32<<<(N + 255) / 256, 256, 0, stream>>>(row_ptr, cursor, N);
    scatter_kernel<<<(E + 255) / 256, 256, 0, stream>>>(esrc, edst, cursor, perm, E);

    // Wt = bf16(W^T) for both MLP weight sets
    {
        dim3 tgrid(DIM / 32, DIM / 32, L);
        dim3 tblk(32, 8);
        transpose_w<<<tgrid, tblk, 0, stream>>>(W1, wt1);
        transpose_w<<<tgrid, tblk, 0, stream>>>(W2, wt2);
    }

    for (int l = 0; l < L; ++l) {
        agg_kernel<<<(N + 3) / 4, 256, 0, stream>>>((const ushort4*)h, row_ptr, perm,
                                                    (ushort4*)z, N);
        mfma_gemm<true><<<256, 256, 0, stream>>>(
            z, wt1 + (size_t)l * DIM * DIM, b1 + (size_t)l * DIM, t, N);
        if (l < L - 1)
            mfma_gemm<true><<<256, 256, 0, stream>>>(
                t, wt2 + (size_t)l * DIM * DIM, b2 + (size_t)l * DIM, h, N);
        else
            mfma_gemm<false><<<256, 256, 0, stream>>>(
                t, wt2 + (size_t)l * DIM * DIM, b2 + (size_t)l * DIM, h, N);
    }

    float* outp   = (float*)d_out;
    float* pooled = outp + (size_t)G * DOUT;
    hipMemsetAsync(pooled, 0, (size_t)G * DIM * sizeof(float), stream);
    gstart_kernel<<<1, 256, 0, stream>>>(bids, gstart, N, G);
    {
        dim3 pgrid(G, PSPLITS);
        pool_kernel<<<pgrid, 64, 0, stream>>>((const ushort4*)h, gstart, pooled);
    }
    out_kernel<<<G, 64, 0, stream>>>(pooled, Wout, bout, outp);
}

// Round 8
// 286.584 us; speedup vs baseline: 1.7592x; 1.0021x over previous
//
#include <hip/hip_runtime.h>

#define DIM 256
#define DOUT 64
#define PSPLITS 16

typedef short bf16x8 __attribute__((ext_vector_type(8)));
typedef float f32x4 __attribute__((ext_vector_type(4)));
typedef unsigned short u16x8 __attribute__((ext_vector_type(8)));

// ---- bf16 helpers (bit-level, RNE) ----
static __device__ __forceinline__ float b2f(unsigned short u) {
    return __uint_as_float(((unsigned)u) << 16);
}
static __device__ __forceinline__ unsigned short f2bf(float f) {
    unsigned u = __float_as_uint(f);
    unsigned r = (u + 0x7fffu + ((u >> 16) & 1u)) >> 16;
    return (unsigned short)r;
}

// ---------------- convert x (f32) -> h (bf16) ----------------
__global__ void cvt_f32_bf16(const float4* __restrict__ src, ushort4* __restrict__ dst, int n4) {
    int i = blockIdx.x * blockDim.x + threadIdx.x;
    int stride = gridDim.x * blockDim.x;
    for (; i < n4; i += stride) {
        float4 v = src[i];
        ushort4 o;
        o.x = f2bf(v.x); o.y = f2bf(v.y); o.z = f2bf(v.z); o.w = f2bf(v.w);
        dst[i] = o;
    }
}

__global__ void copy_i32(const int* __restrict__ src, int* __restrict__ dst, int n) {
    int i = blockIdx.x * blockDim.x + threadIdx.x;
    if (i < n) dst[i] = src[i];
}

// ---------------- CSR build ----------------
__global__ void hist_kernel(const int* __restrict__ dst, int* __restrict__ deg, int E) {
    int i = blockIdx.x * blockDim.x + threadIdx.x;
    if (i < E) atomicAdd(&deg[dst[i]], 1);
}

__global__ void scan_kernel(const int* __restrict__ deg, int* __restrict__ row_ptr, int n) {
    __shared__ int sums[256];
    int t = threadIdx.x;
    int chunk = (n + 255) / 256;
    int lo = t * chunk;
    int hi = min(lo + chunk, n);
    int s = 0;
    for (int i = lo; i < hi; ++i) s += deg[i];
    sums[t] = s;
    __syncthreads();
    for (int off = 1; off < 256; off <<= 1) {
        int v = (t >= off) ? sums[t - off] : 0;
        __syncthreads();
        sums[t] += v;
        __syncthreads();
    }
    int excl = (t == 0) ? 0 : sums[t - 1];
    int run = excl;
    for (int i = lo; i < hi; ++i) { row_ptr[i] = run; run += deg[i]; }
    if (t == 255) row_ptr[n] = run;
}

__global__ void scatter_kernel(const int* __restrict__ src, const int* __restrict__ dst,
                               int* __restrict__ cursor, int* __restrict__ perm, int E) {
    int i = blockIdx.x * blockDim.x + threadIdx.x;
    if (i < E) {
        int d = dst[i];
        int p = atomicAdd(&cursor[d], 1);
        perm[p] = src[i];
    }
}

// ---------------- transpose + convert W [K][N] f32 -> Wt [N][K] bf16 ----------------
__global__ void transpose_w(const float* __restrict__ W, unsigned short* __restrict__ Wt) {
    __shared__ float tile[32][33];
    int l = blockIdx.z;
    int k0 = blockIdx.x * 32, n0 = blockIdx.y * 32;
    const float* Wl = W + (size_t)l * DIM * DIM;
    unsigned short* Wtl = Wt + (size_t)l * DIM * DIM;
    int tx = threadIdx.x, ty = threadIdx.y;
    for (int i = ty; i < 32; i += 8)
        tile[i][tx] = Wl[(size_t)(k0 + i) * DIM + n0 + tx];
    __syncthreads();
    for (int i = ty; i < 32; i += 8)
        Wtl[(size_t)(n0 + i) * DIM + k0 + tx] = f2bf(tile[tx][i]);
}

// ---------------- aggregation (bf16): z = h + sum_{e: dst=n} h[src[e]] ----------------
// one wave per node; 16-deep gather batch (covers avg degree in one issue burst)
__global__ void agg_kernel(const ushort4* __restrict__ h4, const int* __restrict__ row_ptr,
                           const int* __restrict__ perm, ushort4* __restrict__ z4, int n) {
    int wave = threadIdx.x >> 6;
    int lane = threadIdx.x & 63;
    int node = blockIdx.x * 4 + wave;
    if (node >= n) return;
    size_t base = (size_t)node * 64 + lane;
    ushort4 hv = h4[base];
    float ax = b2f(hv.x), ay = b2f(hv.y), az = b2f(hv.z), aw = b2f(hv.w);
    int lo = row_ptr[node], hi = row_ptr[node + 1];
    int e = lo;
    for (; e + 16 <= hi; e += 16) {
        ushort4 v[16];
#pragma unroll
        for (int j = 0; j < 16; ++j) {
            int s = perm[e + j];
            v[j] = h4[(size_t)s * 64 + lane];
        }
#pragma unroll
        for (int j = 0; j < 16; ++j) {
            ax += b2f(v[j].x); ay += b2f(v[j].y);
            az += b2f(v[j].z); aw += b2f(v[j].w);
        }
    }
    for (; e + 4 <= hi; e += 4) {
        ushort4 v[4];
#pragma unroll
        for (int j = 0; j < 4; ++j) {
            int s = perm[e + j];
            v[j] = h4[(size_t)s * 64 + lane];
        }
#pragma unroll
        for (int j = 0; j < 4; ++j) {
            ax += b2f(v[j].x); ay += b2f(v[j].y);
            az += b2f(v[j].z); aw += b2f(v[j].w);
        }
    }
    for (; e < hi; ++e) {
        int s0 = perm[e];
        ushort4 v0 = h4[(size_t)s0 * 64 + lane];
        ax += b2f(v0.x); ay += b2f(v0.y); az += b2f(v0.z); aw += b2f(v0.w);
    }
    ushort4 o;
    o.x = f2bf(ax); o.y = f2bf(ay); o.z = f2bf(az); o.w = f2bf(aw);
    z4[base] = o;
}

// ---------------- persistent reg-B bf16 MFMA GEMM ----------------
// Grid = 512 blocks (2 blocks/CU -> 2 waves/SIMD, the VGPR-allowed max).
// Block b: W-half = b&1 (cols half*128..+128, 64 KB LDS), mslice = b>>1 (0..255).
// Wave w: n-panel = half*128 + (w&1)*64; m-tiles t = mslice*2+(w>>1) + 512*i (2-3 tiles).
// Wave reg-caches its 64x256 B-panel (32 bf16x8 = 128 VGPR); main loop has NO LDS/barrier.
template <bool RELU>
__global__ __launch_bounds__(256, 2) void mfma_gemm(const unsigned short* __restrict__ A,
                                                    const unsigned short* __restrict__ Bt,
                                                    const float* __restrict__ bias,
                                                    unsigned short* __restrict__ C, int M) {
    __shared__ unsigned short Bs[128 * 256];   // [col][k] swizzled, 64 KB
    const int tid = threadIdx.x;
    const int wave = tid >> 6;
    const int lane = tid & 63;
    const int l15 = lane & 15;
    const int g4 = lane >> 4;                  // 0..3
    const int half = blockIdx.x & 1;
    const int mslice = blockIdx.x >> 1;        // 0..255
    const int NT = (M + 15) / 16;              // m-tiles (1250)

    // ---- stage W half-panel (128 cols x 256 k) into swizzled LDS ----
    {
        const char* gsrc = (const char*)&Bt[(size_t)half * 128 * 256];
#pragma unroll
        for (int jj = 0; jj < 16; ++jj) {
            int chunk = tid + jj * 256;        // 16B chunks, 4096 total
            int col = chunk >> 5;              // 32 chunks per 512B col
            int kbyte = (chunk & 31) * 16;
            *reinterpret_cast<u16x8*>((char*)Bs + col * 512 + (kbyte ^ ((col & 7) << 4))) =
                *reinterpret_cast<const u16x8*>(gsrc + col * 512 + kbyte);
        }
    }
    __syncthreads();

    // ---- reg-cache this wave's 64-col B panel: b[n][k8] ----
    bf16x8 b[4][8];
#pragma unroll
    for (int n = 0; n < 4; ++n) {
        const int col = (wave & 1) * 64 + n * 16 + l15;  // local col in 128-panel
        const char* cbase = (const char*)Bs + col * 512;
        const int sw = (col & 7) << 4;
#pragma unroll
        for (int k8 = 0; k8 < 8; ++k8) {
            int kbyte = (k8 * 32 + g4 * 8) * 2;
            b[n][k8] = *reinterpret_cast<const bf16x8*>(cbase + (kbyte ^ sw));
        }
    }

    // bias preload
    const int ncol0 = half * 128 + (wave & 1) * 64;
    float bv[4];
#pragma unroll
    for (int n = 0; n < 4; ++n) bv[n] = bias[ncol0 + n * 16 + l15];

    const int base = mslice * 2 + (wave >> 1);  // 0..511

    auto loadA = [&](bf16x8 (&a)[8], int t) {
        int r = t * 16 + l15;
        if (r >= M) r = M - 1;
        const unsigned short* arow = &A[(size_t)r * 256];
#pragma unroll
        for (int k8 = 0; k8 < 8; ++k8)
            a[k8] = *reinterpret_cast<const bf16x8*>(arow + k8 * 32 + g4 * 8);
    };

    auto computeStore = [&](bf16x8 (&a)[8], int t) {
        f32x4 acc[4] = {};
#pragma unroll
        for (int k8 = 0; k8 < 8; ++k8)
#pragma unroll
            for (int n = 0; n < 4; ++n)
                acc[n] = __builtin_amdgcn_mfma_f32_16x16x32_bf16(a[k8], b[n][k8], acc[n], 0, 0, 0);
        int r0 = t * 16 + g4 * 4;
#pragma unroll
        for (int n = 0; n < 4; ++n) {
            int col = ncol0 + n * 16 + l15;
#pragma unroll
            for (int r = 0; r < 4; ++r) {
                int row = r0 + r;
                if (row < M) {
                    float v = acc[n][r] + bv[n];
                    if (RELU) v = fmaxf(v, 0.f);
                    C[(size_t)row * 256 + col] = f2bf(v);
                }
            }
        }
    };

    bf16x8 a0[8], a1[8];
    int t = base;
    if (t >= NT) return;
    loadA(a0, t);
#pragma unroll 1
    for (int rep = 0; rep < 2; ++rep) {
        if (t >= NT) break;
        if (t + 512 < NT) loadA(a1, t + 512);
        computeStore(a0, t);
        t += 512;
        if (t >= NT) break;
        if (t + 512 < NT) loadA(a0, t + 512);
        computeStore(a1, t);
        t += 512;
    }
}

// ---------------- pooling ----------------
__global__ void gstart_kernel(const int* __restrict__ bids, int* __restrict__ gstart,
                              int n, int G) {
    int g = blockIdx.x * blockDim.x + threadIdx.x;
    if (g > G) return;
    if (g == G) { gstart[G] = n; return; }
    int lo = 0, hi = n;
    while (lo < hi) {
        int mid = (lo + hi) >> 1;
        if (bids[mid] < g) lo = mid + 1; else hi = mid;
    }
    gstart[g] = lo;
}

__global__ void pool_kernel(const ushort4* __restrict__ h4, const int* __restrict__ gstart,
                            float* __restrict__ pooled) {
    int g = blockIdx.x;
    int split = blockIdx.y;
    int lane = threadIdx.x;   // 0..63
    int lo = gstart[g], hi = gstart[g + 1];
    int cnt = hi - lo;
    int chunk = (cnt + PSPLITS - 1) / PSPLITS;
    int s0 = lo + split * chunk;
    int s1 = min(s0 + chunk, hi);
    if (s0 >= s1) return;
    float ax = 0.f, ay = 0.f, az = 0.f, aw = 0.f;
    for (int nd = s0; nd < s1; ++nd) {
        ushort4 v = h4[(size_t)nd * 64 + lane];
        ax += b2f(v.x); ay += b2f(v.y); az += b2f(v.z); aw += b2f(v.w);
    }
    float* p = &pooled[(size_t)g * DIM + lane * 4];
    atomicAdd(p + 0, ax);
    atomicAdd(p + 1, ay);
    atomicAdd(p + 2, az);
    atomicAdd(p + 3, aw);
}

__global__ void out_kernel(const float* __restrict__ pooled, const float* __restrict__ Wout,
                           const float* __restrict__ bout, float* __restrict__ out) {
    __shared__ float p[DIM];
    int g = blockIdx.x;
    for (int d = threadIdx.x; d < DIM; d += blockDim.x) p[d] = pooled[(size_t)g * DIM + d];
    __syncthreads();
    int o = threadIdx.x;
    if (o < DOUT) {
        float acc = bout[o];
        for (int d = 0; d < DIM; ++d) acc += p[d] * Wout[(size_t)d * DOUT + o];
        out[(size_t)g * DOUT + o] = acc;
    }
}

// ---------------- launch ----------------
extern "C" void kernel_launch(void* const* d_in, const int* in_sizes, int n_in,
                              void* d_out, int out_size, void* d_ws, size_t ws_size,
                              hipStream_t stream) {
    const float* x    = (const float*)d_in[0];
    const int*   esrc = (const int*)d_in[1];
    const int*   edst = (const int*)d_in[2];
    const int*   bids = (const int*)d_in[3];
    const float* W1   = (const float*)d_in[4];
    const float* b1   = (const float*)d_in[5];
    const float* W2   = (const float*)d_in[6];
    const float* b2   = (const float*)d_in[7];
    const float* Wout = (const float*)d_in[8];
    const float* bout = (const float*)d_in[9];

    const int N = in_sizes[3];             // 20000
    const int E = in_sizes[1];             // 320000
    const int L = in_sizes[5] / DIM;       // 4
    const int G = out_size / (DOUT + DIM); // 128

    char* ws = (char*)d_ws;
    size_t off = 0;
    auto carve = [&](size_t bytes) -> char* {
        char* p = ws + off;
        off = (off + bytes + 255) & ~(size_t)255;
        return p;
    };
    int* row_ptr = (int*)carve((size_t)(N + 1) * sizeof(int));
    int* cursor  = (int*)carve((size_t)N * sizeof(int));
    int* perm    = (int*)carve((size_t)E * sizeof(int));
    int* gstart  = (int*)carve((size_t)(G + 1) * sizeof(int));
    unsigned short* h   = (unsigned short*)carve((size_t)N * DIM * 2);
    unsigned short* z   = (unsigned short*)carve((size_t)N * DIM * 2);
    unsigned short* t   = (unsigned short*)carve((size_t)N * DIM * 2);
    unsigned short* wt1 = (unsigned short*)carve((size_t)L * DIM * DIM * 2);
    unsigned short* wt2 = (unsigned short*)carve((size_t)L * DIM * DIM * 2);
    (void)ws_size;

    // h = bf16(x)
    cvt_f32_bf16<<<2048, 256, 0, stream>>>((const float4*)x, (ushort4*)h, N * (DIM / 4));

    // CSR build (cursor doubles as degree scratch)
    hipMemsetAsync(cursor, 0, (size_t)N * sizeof(int), stream);
    hist_kernel<<<(E + 255) / 256, 256, 0, stream>>>(edst, cursor, E);
    scan_kernel<<<1, 256, 0, stream>>>(cursor, row_ptr, N);
    copy_i32<<<(N + 255) / 256, 256, 0, stream>>>(row_ptr, cursor, N);
    scatter_kernel<<<(E + 255) / 256, 256, 0, stream>>>(esrc, edst, cursor, perm, E);

    // Wt = bf16(W^T) for both MLP weight sets
    {
        dim3 tgrid(DIM / 32, DIM / 32, L);
        dim3 tblk(32, 8);
        transpose_w<<<tgrid, tblk, 0, stream>>>(W1, wt1);
        transpose_w<<<tgrid, tblk, 0, stream>>>(W2, wt2);
    }

    for (int l = 0; l < L; ++l) {
        agg_kernel<<<(N + 3) / 4, 256, 0, stream>>>((const ushort4*)h, row_ptr, perm,
                                                    (ushort4*)z, N);
        mfma_gemm<true><<<512, 256, 0, stream>>>(
            z, wt1 + (size_t)l * DIM * DIM, b1 + (size_t)l * DIM, t, N);
        if (l < L - 1)
            mfma_gemm<true><<<512, 256, 0, stream>>>(
                t, wt2 + (size_t)l * DIM * DIM, b2 + (size_t)l * DIM, h, N);
        else
            mfma_gemm<false><<<512, 256, 0, stream>>>(
                t, wt2 + (size_t)l * DIM * DIM, b2 + (size_t)l * DIM, h, N);
    }

    float* outp   = (float*)d_out;
    float* pooled = outp + (size_t)G * DOUT;
    hipMemsetAsync(pooled, 0, (size_t)G * DIM * sizeof(float), stream);
    gstart_kernel<<<1, 256, 0, stream>>>(bids, gstart, N, G);
    {
        dim3 pgrid(G, PSPLITS);
        pool_kernel<<<pgrid, 64, 0, stream>>>((const ushort4*)h, gstart, pooled);
    }
    out_kernel<<<G, 64, 0, stream>>>(pooled, Wout, bout, outp);
}